// Round 2
// baseline (78.369 us; speedup 1.0000x reference)
//
#include <hip/hip_runtime.h>
#include <math.h>

#define HW 256
#define MINNORM 1.17549435e-38f   // 2^-126, f32 min normal

// R14: ILP-2. R13 post-mortem: total chains are capped at 1024 (=SIMD count),
// so TLP is maxed at 1 chain/SIMD in ANY layout; per-SIMD issue was conserved
// R12->R13 (4 waves x 33 ops vs 1 wave x 36 ops) -> only -7%. The wall is the
// serial per-step chain (mul -> 2 adds -> 4 DPP w/ hazard waits -> fmax ->
// rcp -> mul) with stalls exposed at 1 chain/wave (~250 cyc/step vs ~72 issue).
// Fix: interleave TWO independent batch-set chains (A,B) per wave — 8 batches
// per wave (4 in lanes x 2 in register sets), 128 blocks. A's DPP/rcp wait
// states are filled by B's ops (same mechanism as R12's dual x/y reduction,
// applied at recurrence granularity).
// NUMERICS: per-batch state path is BIT-IDENTICAL to passing R13 (same op
// sequence, same DPP ctrls 0xB1/0x4E/0x128/0x124, same cd0 init, same loads);
// only cross-chain instruction interleaving differs. Output logf kept precise
// (absmax has been exactly 0.125 twice; not risking a knife-edge threshold on
// an output-only ulp change).
// Dead rows ride the normal path: cd==0 absorbs (0*m=0, 0*invn=0), pz=+/-0
// == ref's closed form; wave early-exits only when ALL 8 batches are dead.
// HARD-WON (inherited):
//  R10: state path must replicate flush+normalize op-for-op each step.
//  R11: 0-sample p_z must be a direct nonneg sum (never S - p2).
//  R13: clip dropped ONLY because cd[j]==0 exactly for j<csf / j>=42 (their
//       out-of-clip pg contributes +/-0 to every sum); invariant inductive.

template <int CTRL>
__device__ __forceinline__ float dpp_add(float x) {
    // x + dpp_perm(x); quad_perm/ror have no OOB lanes
    int s = __builtin_amdgcn_update_dpp(0, __builtin_bit_cast(int, x),
                                        CTRL, 0xf, 0xf, true);
    return x + __builtin_bit_cast(float, s);
}

// Bit-uniform row-of-16 QUAD total: four independent chains (A-state, A-pz,
// B-state, B-pz) interleaved stage-by-stage so each chain's VALU->DPP hazard
// window is filled by the other three chains' ops.
// quad xor1 (0xB1), quad xor2 (0x4E): commutative-pair adds -> quad-uniform.
// row_ror:8 (0x128), row_ror:4 (0x124): bit-uniform total in all 16 lanes.
__device__ __forceinline__ void row_total4(float xa, float ya,
                                           float xb, float yb,
                                           float& sxa, float& sya,
                                           float& sxb, float& syb) {
    xa = dpp_add<0xB1>(xa);  ya = dpp_add<0xB1>(ya);
    xb = dpp_add<0xB1>(xb);  yb = dpp_add<0xB1>(yb);
    xa = dpp_add<0x4E>(xa);  ya = dpp_add<0x4E>(ya);
    xb = dpp_add<0x4E>(xb);  yb = dpp_add<0x4E>(yb);
    xa = dpp_add<0x128>(xa); ya = dpp_add<0x128>(ya);
    xb = dpp_add<0x128>(xb); yb = dpp_add<0x128>(yb);
    xa = dpp_add<0x124>(xa); ya = dpp_add<0x124>(ya);
    xb = dpp_add<0x124>(xb); yb = dpp_add<0x124>(yb);
    sxa = xa; sya = ya; sxb = xb; syb = yb;
}

__global__ void __launch_bounds__(64, 1)
spair_count_kl(const float* __restrict__ z_pres,
               const float* __restrict__ z_prob,
               float* __restrict__ out) {
    // f32 denorm mode = flush in+out (FP_DENORM[1:0]=0), matching XLA FTZ.
    float tok;
    asm volatile("s_setreg_imm32_b32 hwreg(HW_REG_MODE, 4, 2), 0\n\t"
                 "v_mov_b32 %0, 0" : "=v"(tok));

    __shared__ float invt[HW];

    const int lane = threadIdx.x;        // 0..63
    const int l16  = lane & 15;          // lane within row
    const int row  = lane >> 4;          // 0..3
    const int bA   = blockIdx.x * 8 + row;       // set A batch
    const int bB   = bA + 4;                     // set B batch

    // 1/den table, bit-identical to 1.0f/(float)(HW-i) (correctly-rounded div)
#pragma unroll
    for (int i = 0; i < 4; ++i)
        invt[i * 64 + lane] = 1.0f / (float)(HW - (i * 64 + lane));
    __syncthreads();

    // ---- cd0 init (R4..R9 semantics, verbatim math): j = slot*16+l16 ----
    const float e2f = (float)exp(2.0);                    // f32(exp(2))
    const float pf  = (float)(1.0 / ((double)e2f + 1.0)); // p in f32
    const double pd = (double)pf;
    const double l2p = log2(pd);
    float cdA0, cdA1, cdA2;
    {
        float c[3];
#pragma unroll
        for (int sl = 0; sl < 3; ++sl) {
            const int j = sl * 16 + l16;
            const double powj = exp2((double)j * l2p);     // accurate p^j
            float v = (float)((1.0 - pd) * powj);          // (1-p)*p^j, f32
            c[sl] = (v < MINNORM) ? 0.0f : v;              // j>=42 flushes
        }
        float ssum = (c[0] + c[1]) + c[2];
        ssum = dpp_add<0xB1>(ssum);  ssum = dpp_add<0x4E>(ssum);
        ssum = dpp_add<0x128>(ssum); ssum = dpp_add<0x124>(ssum);
        cdA0 = c[0] / ssum; cdA1 = c[1] / ssum; cdA2 = c[2] / ssum;
    }
    cdA0 += tok; cdA1 += tok; cdA2 += tok;   // order recurrence after setreg
    float cdB0 = cdA0, cdB1 = cdA1, cdB2 = cdA2;
    float csfA = tok, csfB = tok;
    const float jf0 = (float)l16;
    const float jf1 = (float)(16 + l16);
    const float jf2 = (float)(32 + l16);

    const float* presA = z_pres + (size_t)bA * HW;
    const float* probA = z_prob + (size_t)bA * HW;
    float*       outA  = out    + (size_t)bA * HW;
    const float* presB = z_pres + (size_t)bB * HW;
    const float* probB = z_prob + (size_t)bB * HW;
    float*       outB  = out    + (size_t)bB * HW;

    bool dead = false;

#pragma unroll 1
    for (int k = 0; k < 16; ++k) {
        float mypzA = 0.0f, mypzB = 0.0f;  // lane captures step i = k*16 + l16
        float p2lA = 0.0f, p2lB = 0.0f;
        if (!dead) {
#pragma unroll
            for (int c4 = 0; c4 < 4; ++c4) {
                // row-uniform 16B chunks: 4 samples each set + 4 shared 1/den
                const float4 zpA4 = *reinterpret_cast<const float4*>(presA + k * 16 + c4 * 4);
                const float4 zpB4 = *reinterpret_cast<const float4*>(presB + k * 16 + c4 * 4);
                const float4 iv4  = *reinterpret_cast<const float4*>(&invt[k * 16 + c4 * 4]);
#pragma unroll
                for (int u = 0; u < 4; ++u) {
                    const int ii = c4 * 4 + u;   // step within k-chunk, 0..15
                    const float zpA = (u == 0) ? zpA4.x : (u == 1) ? zpA4.y
                                    : (u == 2) ? zpA4.z : zpA4.w;
                    const float zpB = (u == 0) ? zpB4.x : (u == 1) ? zpB4.y
                                    : (u == 2) ? zpB4.z : zpB4.w;
                    const float inv = (u == 0) ? iv4.x : (u == 1) ? iv4.y
                                    : (u == 2) ? iv4.z : iv4.w;

                    // sample = round-half-even in {0,1}; per-set
                    const float sA    = rintf(zpA);
                    const float sB    = rintf(zpB);
                    const float sgnA  = fmaf(sA, 2.0f, -1.0f);   // +1/-1 exact
                    const float sgnB  = fmaf(sB, 2.0f, -1.0f);
                    const float baseA = 1.0f - sA;               // 0/+1 exact
                    const float baseB = 1.0f - sB;

                    // pg = (j - csf)*inv (clip inert: cd==0 on out-of-clip)
                    const float tA0 = jf0 - csfA, tA1 = jf1 - csfA, tA2 = jf2 - csfA;
                    const float tB0 = jf0 - csfB, tB1 = jf1 - csfB, tB2 = jf2 - csfB;
                    const float pgA0 = tA0 * inv, pgA1 = tA1 * inv, pgA2 = tA2 * inv;
                    const float pgB0 = tB0 * inv, pgB1 = tB1 * inv, pgB2 = tB2 * inv;

                    // mult = s ? pg : 1-pg, single-rounded fma (bit-equal)
                    const float mA0 = fmaf(pgA0, sgnA, baseA);
                    const float mA1 = fmaf(pgA1, sgnA, baseA);
                    const float mA2 = fmaf(pgA2, sgnA, baseA);
                    const float mB0 = fmaf(pgB0, sgnB, baseB);
                    const float mB1 = fmaf(pgB1, sgnB, baseB);
                    const float mB2 = fmaf(pgB2, sgnB, baseB);

                    // ---- STATE + OUTPUT products (HW-FTZ) ----
                    const float prA0 = cdA0 * mA0, prA1 = cdA1 * mA1, prA2 = cdA2 * mA2;
                    const float prB0 = cdB0 * mB0, prB1 = cdB1 * mB1, prB2 = cdB2 * mB2;
                    const float yA0 = cdA0 * pgA0, yA1 = cdA1 * pgA1, yA2 = cdA2 * pgA2;
                    const float yB0 = cdB0 * pgB0, yB1 = cdB1 * pgB1, yB2 = cdB2 * pgB2;

                    float p2A, p1sA, p2B, p1sB;
                    row_total4((prA0 + prA1) + prA2, (yA0 + yA1) + yA2,
                               (prB0 + prB1) + prB2, (yB0 + yB1) + yB2,
                               p2A, p1sA, p2B, p1sB);

                    const float normA = fmaxf(p2A, 1e-6f);   // clip(sum,1e-6,inf)
                    const float normB = fmaxf(p2B, 1e-6f);
                    const float invnA = __builtin_amdgcn_rcpf(normA);
                    const float invnB = __builtin_amdgcn_rcpf(normB);
                    cdA0 = prA0 * invnA; cdA1 = prA1 * invnA; cdA2 = prA2 * invnA;
                    cdB0 = prB0 * invnB; cdB1 = prB1 * invnB; cdB2 = prB2 * invnB;
                    csfA += sA;
                    csfB += sB;

                    // s1: ref p_z terms == norm terms exactly -> p2.
                    const float pzA = (sA != 0.0f) ? p2A : p1sA;
                    const float pzB = (sB != 0.0f) ? p2B : p1sB;
                    mypzA = (l16 == ii) ? pzA : mypzA;
                    mypzB = (l16 == ii) ? pzB : mypzB;
                    p2lA = p2A;       // dead rows stay exactly 0
                    p2lB = p2B;
                }
            }
            // wave exits only when ALL 8 batches are dead; dead rows meanwhile
            // produce pz = +/-0 through the normal path (== ref closed form).
            if (__ballot((p2lA != 0.0f) || (p2lB != 0.0f)) == 0ULL) dead = true;
        }

        // KL for this lane's step (i = k*16 + l16); mypz==0 on dead steps is
        // exactly the ref's p_z=0 closed form. (Precise logf: output path, but
        // absmax sits at exactly 0.125 — not risking a knife-edge threshold.)
        {
            const float prob = probA[k * 16 + l16];
            const float pz = mypzA;
            const float kl = prob * (logf(prob + 1e-9f) - logf(pz + 1e-9f))
                           + (1.0f - prob) * (logf((1.0f - prob) + 1e-9f)
                                            - logf((1.0f - pz) + 1e-9f));
            outA[k * 16 + l16] = kl;
        }
        {
            const float prob = probB[k * 16 + l16];
            const float pz = mypzB;
            const float kl = prob * (logf(prob + 1e-9f) - logf(pz + 1e-9f))
                           + (1.0f - prob) * (logf((1.0f - prob) + 1e-9f)
                                            - logf((1.0f - pz) + 1e-9f));
            outB[k * 16 + l16] = kl;
        }
    }
}

extern "C" void kernel_launch(void* const* d_in, const int* in_sizes, int n_in,
                              void* d_out, int out_size, void* d_ws, size_t ws_size,
                              hipStream_t stream) {
    const float* z_pres = (const float*)d_in[0];      // setup_inputs order
    const float* z_prob = (const float*)d_in[1];
    float* out = (float*)d_out;
    const int nbatch = in_sizes[0] / HW;              // 1024
    spair_count_kl<<<dim3(nbatch / 8), dim3(64), 0, stream>>>(z_pres, z_prob, out);
}

// Round 4
// 65.457 us; speedup vs baseline: 1.1973x; 1.1973x over previous
//
#include <hip/hip_runtime.h>
#include <math.h>

#define HW 256
#define MINNORM 1.17549435e-38f   // 2^-126, f32 min normal

// R16: revert R15's lazy-norm (FAILED, absmax 15.4: intermediates u=q*m live
// at prodm*norm_{t-1} scale -> FTZ flush fires up to 1e6..1e30x early -> death
// timing shifts -> trajectory divergence via the clip-resurrection knife-edge).
// LAW (R14+R15): ulp-class reassociation passes (~1 bf16 ulp absmax);
// SCALE-class shifts of FTZ flush points are fatal. State path must keep
// every intermediate at ref's scale.
//
// R16 = R13's EXACT per-step numerics (eager normalize, same op sequence,
// same DPP ctrls, same fold order) + scheduling-only changes:
//  (1) double-buffered zp/iv loads at k granularity: loads for k+1 issue
//      before k's 16-step body, so vmcnt/lgkmcnt waits overlap ~2500 cyc of
//      compute instead of being exposed per chunk;
//  (2) KL deferred to epilogue: per-k pz stashed in pre-zeroed LDS (dead k's
//      read exact +0 == R13's mypz=0), so 4x logf + prob loads + stores leave
//      the latency-critical recurrence loop;
//  (3) total death breaks the k-loop outright (epilogue covers the tail).
// R14 post-mortem (kept for the record): merging 2 chains/wave doubles
// per-wave issue while freed SIMDs idle -> 1.40x regression; layout stays
// 256 waves x 4 batches/wave x 16 lanes x 3 slots.
// HARD-WON (inherited):
//  R10: state path replicates flush+normalize op-for-op each step at ref's
//       SCALE (ulp noise OK, scale noise fatal — reconfirmed by R15).
//  R11: 0-sample p_z is a direct nonneg sum (never S - p2).
//  R13: clip dropped ONLY because cd[j]==0 exactly for j<csf / j>=42 (their
//       out-of-clip pg contributes +/-0 to every sum); invariant inductive.

template <int CTRL>
__device__ __forceinline__ float dpp_add(float x) {
    // x + dpp_perm(x); quad_perm/ror have no OOB lanes
    int s = __builtin_amdgcn_update_dpp(0, __builtin_bit_cast(int, x),
                                        CTRL, 0xf, 0xf, true);
    return x + __builtin_bit_cast(float, s);
}

// Bit-uniform row-of-16 dual total, stages interleaved (independent chains
// hide each other's VALU->DPP wait states).
// quad xor1 (0xB1), quad xor2 (0x4E): commutative-pair adds -> quad-uniform.
// row_ror:8 (0x128), row_ror:4 (0x124): bit-uniform total in all 16 lanes.
__device__ __forceinline__ void row_total2(float x, float y,
                                           float& sx, float& sy) {
    x = dpp_add<0xB1>(x);   y = dpp_add<0xB1>(y);
    x = dpp_add<0x4E>(x);   y = dpp_add<0x4E>(y);
    x = dpp_add<0x128>(x);  y = dpp_add<0x128>(y);
    x = dpp_add<0x124>(x);  y = dpp_add<0x124>(y);
    sx = x; sy = y;
}

__global__ void __launch_bounds__(64, 1)
spair_count_kl(const float* __restrict__ z_pres,
               const float* __restrict__ z_prob,
               float* __restrict__ out) {
    // f32 denorm mode = flush in+out (FP_DENORM[1:0]=0), matching XLA FTZ.
    float tok;
    asm volatile("s_setreg_imm32_b32 hwreg(HW_REG_MODE, 4, 2), 0\n\t"
                 "v_mov_b32 %0, 0" : "=v"(tok));

    __shared__ float invt[HW];
    __shared__ float pzbuf[4 * 16 * 16];   // [row][k][l16], pre-zeroed

    const int lane = threadIdx.x;        // 0..63
    const int l16  = lane & 15;          // lane within row
    const int row  = lane >> 4;          // 0..3
    const int b    = blockIdx.x * 4 + row;

    // 1/den table, bit-identical to 1.0f/(float)(HW-i) (correctly-rounded div)
#pragma unroll
    for (int i = 0; i < 4; ++i)
        invt[i * 64 + lane] = 1.0f / (float)(HW - (i * 64 + lane));
    // zero the pz stash: dead/unreached k's must read exact +0
#pragma unroll
    for (int i = 0; i < 16; ++i)
        pzbuf[i * 64 + lane] = 0.0f;
    __syncthreads();

    // ---- cd0 init (R4..R9 semantics, verbatim math): j = slot*16+l16 ----
    const float e2f = (float)exp(2.0);                    // f32(exp(2))
    const float pf  = (float)(1.0 / ((double)e2f + 1.0)); // p in f32
    const double pd = (double)pf;
    const double l2p = log2(pd);
    float cd0, cd1, cd2;
    {
        float c[3];
#pragma unroll
        for (int sl = 0; sl < 3; ++sl) {
            const int j = sl * 16 + l16;
            const double powj = exp2((double)j * l2p);     // accurate p^j
            float v = (float)((1.0 - pd) * powj);          // (1-p)*p^j, f32
            c[sl] = (v < MINNORM) ? 0.0f : v;              // j>=42 flushes
        }
        float ssum = (c[0] + c[1]) + c[2];
        ssum = dpp_add<0xB1>(ssum);  ssum = dpp_add<0x4E>(ssum);
        ssum = dpp_add<0x128>(ssum); ssum = dpp_add<0x124>(ssum);
        cd0 = c[0] / ssum; cd1 = c[1] / ssum; cd2 = c[2] / ssum;
    }
    cd0 += tok; cd1 += tok; cd2 += tok;   // order recurrence after setreg
    float csf = tok;
    const float jf0 = (float)l16;
    const float jf1 = (float)(16 + l16);
    const float jf2 = (float)(32 + l16);

    const float* presb = z_pres + (size_t)b * HW;

    // 16-step body for chunk k; arithmetic is op-for-op R13 (passing).
    auto do_k = [&](int k, const float4* zp, const float4* iv) -> float {
        float mypz = 0.0f;        // this lane captures step i = k*16 + l16
        float nlast = 0.0f;
#pragma unroll
        for (int c4 = 0; c4 < 4; ++c4) {
            const float4 zp4 = zp[c4];
            const float4 iv4 = iv[c4];
#pragma unroll
            for (int u = 0; u < 4; ++u) {
                const int ii = c4 * 4 + u;   // step within k-chunk, 0..15
                const float zpv = (u == 0) ? zp4.x : (u == 1) ? zp4.y
                                : (u == 2) ? zp4.z : zp4.w;
                const float inv = (u == 0) ? iv4.x : (u == 1) ? iv4.y
                                : (u == 2) ? iv4.z : iv4.w;

                // sample = round-half-even in {0,1}
                const float s    = rintf(zpv);
                const float sgn  = fmaf(s, 2.0f, -1.0f);   // +1/-1 exact
                const float base = 1.0f - s;               //  0/+1 exact

                // pg = (j - csf)*inv (clip inert: cd==0 on out-of-clip)
                const float t0 = jf0 - csf, t1 = jf1 - csf, t2 = jf2 - csf;
                const float pg0 = t0 * inv, pg1 = t1 * inv, pg2 = t2 * inv;

                // mult = s ? pg : 1-pg, single-rounded fma (bit-equal)
                const float m0 = fmaf(pg0, sgn, base);
                const float m1 = fmaf(pg1, sgn, base);
                const float m2 = fmaf(pg2, sgn, base);

                // ---- STATE + OUTPUT products (HW-FTZ), ref scale ----
                const float pr0 = cd0 * m0, pr1 = cd1 * m1, pr2 = cd2 * m2;
                const float y0 = cd0 * pg0, y1 = cd1 * pg1, y2 = cd2 * pg2;

                float p2, p1s;
                row_total2((pr0 + pr1) + pr2, (y0 + y1) + y2, p2, p1s);

                const float norm = fmaxf(p2, 1e-6f);   // clip(sum,1e-6,inf)
                const float invn = __builtin_amdgcn_rcpf(norm);
                cd0 = pr0 * invn; cd1 = pr1 * invn; cd2 = pr2 * invn;
                csf += s;

                // s1: ref p_z terms == norm terms exactly -> p2.
                const float pz = (s != 0.0f) ? p2 : p1s;
                mypz = (l16 == ii) ? pz : mypz;
                nlast = p2;       // dead rows produce exactly 0
            }
        }
        pzbuf[(row * 16 + k) * 16 + l16] = mypz;   // off-chain stash
        return nlast;
    };

    // ---- main loop: 2 k's per iteration, double-buffered loads ----
    float4 zpb0[4], ivb0[4], zpb1[4], ivb1[4];
#pragma unroll
    for (int c = 0; c < 4; ++c) {       // initial load: k=0 -> buf0
        zpb0[c] = *reinterpret_cast<const float4*>(presb + c * 4);
        ivb0[c] = *reinterpret_cast<const float4*>(&invt[c * 4]);
    }

#pragma unroll 1
    for (int kk = 0; kk < 8; ++kk) {
        const int k0 = 2 * kk, k1 = 2 * kk + 1;
        // prefetch k1 -> buf1 (first use ~16 steps away)
#pragma unroll
        for (int c = 0; c < 4; ++c) {
            zpb1[c] = *reinterpret_cast<const float4*>(presb + k1 * 16 + c * 4);
            ivb1[c] = *reinterpret_cast<const float4*>(&invt[k1 * 16 + c * 4]);
        }
        const float n0 = do_k(k0, zpb0, ivb0);
        // wave exits only when ALL 4 batches are dead; dead rows meanwhile
        // produce pz = +/-0 through the normal path (== ref closed form).
        if (__ballot(n0 != 0.0f) == 0ULL) break;

        // prefetch k0+2 -> buf0 (clamped; kk==7 load is unused, harmless)
        const int kn = (kk < 7) ? (k0 + 2) : 15;
#pragma unroll
        for (int c = 0; c < 4; ++c) {
            zpb0[c] = *reinterpret_cast<const float4*>(presb + kn * 16 + c * 4);
            ivb0[c] = *reinterpret_cast<const float4*>(&invt[kn * 16 + c * 4]);
        }
        const float n1 = do_k(k1, zpb1, ivb1);
        if (__ballot(n1 != 0.0f) == 0ULL) break;
    }

    // ---- KL epilogue: pure pz-from-LDS + logf, no recurrence dependence ----
    // pz transported bit-exactly through LDS; unreached k's read exact +0,
    // matching ref's p_z=0 closed form (same KL as R13's in-loop path).
    const float* probb = z_prob + (size_t)b * HW;
    float* outb = out + (size_t)b * HW;
#pragma unroll 2
    for (int k = 0; k < 16; ++k) {
        const float pz = pzbuf[(row * 16 + k) * 16 + l16];
        const float prob = probb[k * 16 + l16];
        const float kl = prob * (logf(prob + 1e-9f) - logf(pz + 1e-9f))
                       + (1.0f - prob) * (logf((1.0f - prob) + 1e-9f)
                                        - logf((1.0f - pz) + 1e-9f));
        outb[k * 16 + l16] = kl;   // 64B per row, coalesced
    }
}

extern "C" void kernel_launch(void* const* d_in, const int* in_sizes, int n_in,
                              void* d_out, int out_size, void* d_ws, size_t ws_size,
                              hipStream_t stream) {
    const float* z_pres = (const float*)d_in[0];      // setup_inputs order
    const float* z_prob = (const float*)d_in[1];
    float* out = (float*)d_out;
    const int nbatch = in_sizes[0] / HW;              // 1024
    spair_count_kl<<<dim3(nbatch / 4), dim3(64), 0, stream>>>(z_pres, z_prob, out);
}

// Round 5
// 64.794 us; speedup vs baseline: 1.2095x; 1.0102x over previous
//
#include <hip/hip_runtime.h>
#include <math.h>

#define HW 256
#define MINNORM 1.17549435e-38f   // 2^-126, f32 min normal

// R17 = R16 (passing, 65.5us) + FAST-LOG EPILOGUE only. Hot loop & state path
// byte-identical to R16.
// Rationale: with death-break at k~7, the epilogue's 64 libm logf/lane
// (~1900 instr ~3-4us) is ~1/3 of kernel time. v_log_f32 (HW log2, ~1ulp) x
// ln2 cuts it to ~64 trans + ~160 VALU. Output-path-only change; R14/R16
// proved the reassoc/ulp class passes at absmax ~0.001 vs threshold 0.415.
// KL refactor: kl = ln2*(prob*(Lp-Lz) + (1-prob)*(Lq-Lw)), L* = log2(x+1e-9),
//            = ln2*fma(prob, d1-d2, d2). 1+1e-9 rounds to 1.0f in f32 exactly
// as in ref, so pz=0 dead steps give Lw=0 bit-like ref's closed form.
// LAWS (inherited):
//  R10/R15: state path must keep every intermediate at ref's SCALE (eager
//       renormalize each step; FTZ flush points must not shift). Ulp-class
//       reassociation passes (~1 bf16 ulp absmax); scale-class is fatal.
//  R11: 0-sample p_z is a direct nonneg sum (never S - p2).
//  R13: clip dropped ONLY because cd[j]==0 exactly for j<csf / j>=42.
//  R14: merging chains into one wave doubles per-wave issue while freed SIMDs
//       idle -> regression. Layout stays 256 waves x 4 batches x 16 lanes.
//  R16: k-granularity double-buffered loads + KL deferred via pre-zeroed LDS
//       pzbuf + break on total death.

template <int CTRL>
__device__ __forceinline__ float dpp_add(float x) {
    // x + dpp_perm(x); quad_perm/ror have no OOB lanes
    int s = __builtin_amdgcn_update_dpp(0, __builtin_bit_cast(int, x),
                                        CTRL, 0xf, 0xf, true);
    return x + __builtin_bit_cast(float, s);
}

// Bit-uniform row-of-16 dual total, stages interleaved (independent chains
// hide each other's VALU->DPP wait states).
// quad xor1 (0xB1), quad xor2 (0x4E): commutative-pair adds -> quad-uniform.
// row_ror:8 (0x128), row_ror:4 (0x124): bit-uniform total in all 16 lanes.
__device__ __forceinline__ void row_total2(float x, float y,
                                           float& sx, float& sy) {
    x = dpp_add<0xB1>(x);   y = dpp_add<0xB1>(y);
    x = dpp_add<0x4E>(x);   y = dpp_add<0x4E>(y);
    x = dpp_add<0x128>(x);  y = dpp_add<0x128>(y);
    x = dpp_add<0x124>(x);  y = dpp_add<0x124>(y);
    sx = x; sy = y;
}

// HW log2 (v_log_f32, ~1 ulp). Output path only.
__device__ __forceinline__ float fast_log2(float x) {
#if __has_builtin(__builtin_amdgcn_logf)
    return __builtin_amdgcn_logf(x);
#else
    return __log2f(x);
#endif
}

__global__ void __launch_bounds__(64, 1)
spair_count_kl(const float* __restrict__ z_pres,
               const float* __restrict__ z_prob,
               float* __restrict__ out) {
    // f32 denorm mode = flush in+out (FP_DENORM[1:0]=0), matching XLA FTZ.
    float tok;
    asm volatile("s_setreg_imm32_b32 hwreg(HW_REG_MODE, 4, 2), 0\n\t"
                 "v_mov_b32 %0, 0" : "=v"(tok));

    __shared__ float invt[HW];
    __shared__ float pzbuf[4 * 16 * 16];   // [row][k][l16], pre-zeroed

    const int lane = threadIdx.x;        // 0..63
    const int l16  = lane & 15;          // lane within row
    const int row  = lane >> 4;          // 0..3
    const int b    = blockIdx.x * 4 + row;

    // 1/den table, bit-identical to 1.0f/(float)(HW-i) (correctly-rounded div)
#pragma unroll
    for (int i = 0; i < 4; ++i)
        invt[i * 64 + lane] = 1.0f / (float)(HW - (i * 64 + lane));
    // zero the pz stash: dead/unreached k's must read exact +0
#pragma unroll
    for (int i = 0; i < 16; ++i)
        pzbuf[i * 64 + lane] = 0.0f;
    __syncthreads();

    // ---- cd0 init (R4..R9 semantics, verbatim math): j = slot*16+l16 ----
    const float e2f = (float)exp(2.0);                    // f32(exp(2))
    const float pf  = (float)(1.0 / ((double)e2f + 1.0)); // p in f32
    const double pd = (double)pf;
    const double l2p = log2(pd);
    float cd0, cd1, cd2;
    {
        float c[3];
#pragma unroll
        for (int sl = 0; sl < 3; ++sl) {
            const int j = sl * 16 + l16;
            const double powj = exp2((double)j * l2p);     // accurate p^j
            float v = (float)((1.0 - pd) * powj);          // (1-p)*p^j, f32
            c[sl] = (v < MINNORM) ? 0.0f : v;              // j>=42 flushes
        }
        float ssum = (c[0] + c[1]) + c[2];
        ssum = dpp_add<0xB1>(ssum);  ssum = dpp_add<0x4E>(ssum);
        ssum = dpp_add<0x128>(ssum); ssum = dpp_add<0x124>(ssum);
        cd0 = c[0] / ssum; cd1 = c[1] / ssum; cd2 = c[2] / ssum;
    }
    cd0 += tok; cd1 += tok; cd2 += tok;   // order recurrence after setreg
    float csf = tok;
    const float jf0 = (float)l16;
    const float jf1 = (float)(16 + l16);
    const float jf2 = (float)(32 + l16);

    const float* presb = z_pres + (size_t)b * HW;

    // 16-step body for chunk k; arithmetic is op-for-op R13 (passing).
    auto do_k = [&](int k, const float4* zp, const float4* iv) -> float {
        float mypz = 0.0f;        // this lane captures step i = k*16 + l16
        float nlast = 0.0f;
#pragma unroll
        for (int c4 = 0; c4 < 4; ++c4) {
            const float4 zp4 = zp[c4];
            const float4 iv4 = iv[c4];
#pragma unroll
            for (int u = 0; u < 4; ++u) {
                const int ii = c4 * 4 + u;   // step within k-chunk, 0..15
                const float zpv = (u == 0) ? zp4.x : (u == 1) ? zp4.y
                                : (u == 2) ? zp4.z : zp4.w;
                const float inv = (u == 0) ? iv4.x : (u == 1) ? iv4.y
                                : (u == 2) ? iv4.z : iv4.w;

                // sample = round-half-even in {0,1}
                const float s    = rintf(zpv);
                const float sgn  = fmaf(s, 2.0f, -1.0f);   // +1/-1 exact
                const float base = 1.0f - s;               //  0/+1 exact

                // pg = (j - csf)*inv (clip inert: cd==0 on out-of-clip)
                const float t0 = jf0 - csf, t1 = jf1 - csf, t2 = jf2 - csf;
                const float pg0 = t0 * inv, pg1 = t1 * inv, pg2 = t2 * inv;

                // mult = s ? pg : 1-pg, single-rounded fma (bit-equal)
                const float m0 = fmaf(pg0, sgn, base);
                const float m1 = fmaf(pg1, sgn, base);
                const float m2 = fmaf(pg2, sgn, base);

                // ---- STATE + OUTPUT products (HW-FTZ), ref scale ----
                const float pr0 = cd0 * m0, pr1 = cd1 * m1, pr2 = cd2 * m2;
                const float y0 = cd0 * pg0, y1 = cd1 * pg1, y2 = cd2 * pg2;

                float p2, p1s;
                row_total2((pr0 + pr1) + pr2, (y0 + y1) + y2, p2, p1s);

                const float norm = fmaxf(p2, 1e-6f);   // clip(sum,1e-6,inf)
                const float invn = __builtin_amdgcn_rcpf(norm);
                cd0 = pr0 * invn; cd1 = pr1 * invn; cd2 = pr2 * invn;
                csf += s;

                // s1: ref p_z terms == norm terms exactly -> p2.
                const float pz = (s != 0.0f) ? p2 : p1s;
                mypz = (l16 == ii) ? pz : mypz;
                nlast = p2;       // dead rows produce exactly 0
            }
        }
        pzbuf[(row * 16 + k) * 16 + l16] = mypz;   // off-chain stash
        return nlast;
    };

    // ---- main loop: 2 k's per iteration, double-buffered loads ----
    float4 zpb0[4], ivb0[4], zpb1[4], ivb1[4];
#pragma unroll
    for (int c = 0; c < 4; ++c) {       // initial load: k=0 -> buf0
        zpb0[c] = *reinterpret_cast<const float4*>(presb + c * 4);
        ivb0[c] = *reinterpret_cast<const float4*>(&invt[c * 4]);
    }

#pragma unroll 1
    for (int kk = 0; kk < 8; ++kk) {
        const int k0 = 2 * kk, k1 = 2 * kk + 1;
        // prefetch k1 -> buf1 (first use ~16 steps away)
#pragma unroll
        for (int c = 0; c < 4; ++c) {
            zpb1[c] = *reinterpret_cast<const float4*>(presb + k1 * 16 + c * 4);
            ivb1[c] = *reinterpret_cast<const float4*>(&invt[k1 * 16 + c * 4]);
        }
        const float n0 = do_k(k0, zpb0, ivb0);
        // wave exits only when ALL 4 batches are dead; dead rows meanwhile
        // produce pz = +/-0 through the normal path (== ref closed form).
        if (__ballot(n0 != 0.0f) == 0ULL) break;

        // prefetch k0+2 -> buf0 (clamped; kk==7 load is unused, harmless)
        const int kn = (kk < 7) ? (k0 + 2) : 15;
#pragma unroll
        for (int c = 0; c < 4; ++c) {
            zpb0[c] = *reinterpret_cast<const float4*>(presb + kn * 16 + c * 4);
            ivb0[c] = *reinterpret_cast<const float4*>(&invt[kn * 16 + c * 4]);
        }
        const float n1 = do_k(k1, zpb1, ivb1);
        if (__ballot(n1 != 0.0f) == 0ULL) break;
    }

    // ---- KL epilogue: fast HW-log2 form ----
    // kl = ln2 * (prob*(Lp-Lz) + (1-prob)*(Lq-Lw)), L* = log2(x + 1e-9).
    // pz transported bit-exactly through LDS; unreached k's read exact +0
    // (Lw = log2(1+1e-9 -> 1.0f) = 0, matching ref's p_z=0 closed form).
    // Output-path-only reassoc + ~1ulp HW log: proven-passing class (R14/R16),
    // threshold 0.415 vs current absmax 0.00098.
    const float* probb = z_prob + (size_t)b * HW;
    float* outb = out + (size_t)b * HW;
#pragma unroll 4
    for (int k = 0; k < 16; ++k) {
        const float pz   = pzbuf[(row * 16 + k) * 16 + l16];
        const float prob = probb[k * 16 + l16];
        const float Lp = fast_log2(prob + 1e-9f);
        const float Lz = fast_log2(pz + 1e-9f);
        const float Lq = fast_log2((1.0f - prob) + 1e-9f);
        const float Lw = fast_log2((1.0f - pz) + 1e-9f);
        const float d1 = Lp - Lz;
        const float d2 = Lq - Lw;
        const float kl = 0.6931471805599453f * fmaf(prob, d1 - d2, d2);
        outb[k * 16 + l16] = kl;   // 64B per row, coalesced
    }
}

extern "C" void kernel_launch(void* const* d_in, const int* in_sizes, int n_in,
                              void* d_out, int out_size, void* d_ws, size_t ws_size,
                              hipStream_t stream) {
    const float* z_pres = (const float*)d_in[0];      // setup_inputs order
    const float* z_prob = (const float*)d_in[1];
    float* out = (float*)d_out;
    const int nbatch = in_sizes[0] / HW;              // 1024
    spair_count_kl<<<dim3(nbatch / 4), dim3(64), 0, stream>>>(z_pres, z_prob, out);
}

// Round 6
// 64.555 us; speedup vs baseline: 1.2140x; 1.0037x over previous
//
#include <hip/hip_runtime.h>
#include <math.h>

#define HW 256
#define MINNORM 1.17549435e-38f   // 2^-126, f32 min normal

// R18 = R17 (passing, 64.8us, absmax 9.5e-7) + FINER DEATH GRANULARITY only.
// Post-mortem R17: fast-log bought just 0.7us -> hot loop owns ~23us. Model:
// worst batch dies at csf=42 ~ step 114; chunk-granularity (16) break makes
// the wall wave run 128 steps. Chain is already at minimum depth (mul ->
// 6-deep 48-way sum -> fmax -> rcp -> mul = 10 links; R15 proved the only
// depth-cutter, lazy norm, is scale-fatal). Remaining controllable term:
// check death per 4-step c4 sub-chunk (one extra ballot + uniform branch per
// c4) -> wall ~116 steps, ~9% of hot loop. Control-flow-only: state op
// sequence, DPP ctrls, and all produced values byte-identical; steps skipped
// after total death produce pz=0 exactly as the pre-zeroed pzbuf encodes
// (ref's p_z=0 closed form). Death predicate unchanged (p2==0 is absorbing:
// p2=0 -> all pr=0 -> cd=pr*invn=0 forever), just sampled more often.
// LAWS (inherited):
//  R10/R15: state path must keep every intermediate at ref's SCALE (eager
//       renormalize each step; FTZ flush points must not shift). Ulp-class
//       reassociation passes; scale-class is fatal.
//  R11: 0-sample p_z is a direct nonneg sum (never S - p2).
//  R13: clip dropped ONLY because cd[j]==0 exactly for j<csf / j>=42.
//  R14: merging chains into one wave doubles per-wave issue while freed SIMDs
//       idle -> regression. Layout stays 256 waves x 4 batches x 16 lanes.
//  R16: k-granularity double-buffered loads + KL deferred via pre-zeroed LDS
//       pzbuf + break on total death.
//  R17: epilogue KL via HW v_log_f32 (log2) x ln2; output-path-only.

template <int CTRL>
__device__ __forceinline__ float dpp_add(float x) {
    // x + dpp_perm(x); quad_perm/ror have no OOB lanes
    int s = __builtin_amdgcn_update_dpp(0, __builtin_bit_cast(int, x),
                                        CTRL, 0xf, 0xf, true);
    return x + __builtin_bit_cast(float, s);
}

// Bit-uniform row-of-16 dual total, stages interleaved (independent chains
// hide each other's VALU->DPP wait states).
// quad xor1 (0xB1), quad xor2 (0x4E): commutative-pair adds -> quad-uniform.
// row_ror:8 (0x128), row_ror:4 (0x124): bit-uniform total in all 16 lanes.
__device__ __forceinline__ void row_total2(float x, float y,
                                           float& sx, float& sy) {
    x = dpp_add<0xB1>(x);   y = dpp_add<0xB1>(y);
    x = dpp_add<0x4E>(x);   y = dpp_add<0x4E>(y);
    x = dpp_add<0x128>(x);  y = dpp_add<0x128>(y);
    x = dpp_add<0x124>(x);  y = dpp_add<0x124>(y);
    sx = x; sy = y;
}

// HW log2 (v_log_f32, ~1 ulp). Output path only.
__device__ __forceinline__ float fast_log2(float x) {
#if __has_builtin(__builtin_amdgcn_logf)
    return __builtin_amdgcn_logf(x);
#else
    return __log2f(x);
#endif
}

__global__ void __launch_bounds__(64, 1)
spair_count_kl(const float* __restrict__ z_pres,
               const float* __restrict__ z_prob,
               float* __restrict__ out) {
    // f32 denorm mode = flush in+out (FP_DENORM[1:0]=0), matching XLA FTZ.
    float tok;
    asm volatile("s_setreg_imm32_b32 hwreg(HW_REG_MODE, 4, 2), 0\n\t"
                 "v_mov_b32 %0, 0" : "=v"(tok));

    __shared__ float invt[HW];
    __shared__ float pzbuf[4 * 16 * 16];   // [row][k][l16], pre-zeroed

    const int lane = threadIdx.x;        // 0..63
    const int l16  = lane & 15;          // lane within row
    const int row  = lane >> 4;          // 0..3
    const int b    = blockIdx.x * 4 + row;

    // 1/den table, bit-identical to 1.0f/(float)(HW-i) (correctly-rounded div)
#pragma unroll
    for (int i = 0; i < 4; ++i)
        invt[i * 64 + lane] = 1.0f / (float)(HW - (i * 64 + lane));
    // zero the pz stash: dead/unreached k's must read exact +0
#pragma unroll
    for (int i = 0; i < 16; ++i)
        pzbuf[i * 64 + lane] = 0.0f;
    __syncthreads();

    // ---- cd0 init (R4..R9 semantics, verbatim math): j = slot*16+l16 ----
    const float e2f = (float)exp(2.0);                    // f32(exp(2))
    const float pf  = (float)(1.0 / ((double)e2f + 1.0)); // p in f32
    const double pd = (double)pf;
    const double l2p = log2(pd);
    float cd0, cd1, cd2;
    {
        float c[3];
#pragma unroll
        for (int sl = 0; sl < 3; ++sl) {
            const int j = sl * 16 + l16;
            const double powj = exp2((double)j * l2p);     // accurate p^j
            float v = (float)((1.0 - pd) * powj);          // (1-p)*p^j, f32
            c[sl] = (v < MINNORM) ? 0.0f : v;              // j>=42 flushes
        }
        float ssum = (c[0] + c[1]) + c[2];
        ssum = dpp_add<0xB1>(ssum);  ssum = dpp_add<0x4E>(ssum);
        ssum = dpp_add<0x128>(ssum); ssum = dpp_add<0x124>(ssum);
        cd0 = c[0] / ssum; cd1 = c[1] / ssum; cd2 = c[2] / ssum;
    }
    cd0 += tok; cd1 += tok; cd2 += tok;   // order recurrence after setreg
    float csf = tok;
    const float jf0 = (float)l16;
    const float jf1 = (float)(16 + l16);
    const float jf2 = (float)(32 + l16);

    const float* presb = z_pres + (size_t)b * HW;

    // 16-step body for chunk k; arithmetic is op-for-op R13 (passing).
    // Returns wave-uniform alive flag; death checked per 4-step sub-chunk.
    auto do_k = [&](int k, const float4* zp, const float4* iv) -> bool {
        float mypz = 0.0f;        // this lane captures step i = k*16 + l16
        bool alive = true;
#pragma unroll
        for (int c4 = 0; c4 < 4; ++c4) {
            if (alive) {          // wave-uniform (ballot-derived)
                const float4 zp4 = zp[c4];
                const float4 iv4 = iv[c4];
                float nlast = 0.0f;
#pragma unroll
                for (int u = 0; u < 4; ++u) {
                    const int ii = c4 * 4 + u;   // step within k-chunk, 0..15
                    const float zpv = (u == 0) ? zp4.x : (u == 1) ? zp4.y
                                    : (u == 2) ? zp4.z : zp4.w;
                    const float inv = (u == 0) ? iv4.x : (u == 1) ? iv4.y
                                    : (u == 2) ? iv4.z : iv4.w;

                    // sample = round-half-even in {0,1}
                    const float s    = rintf(zpv);
                    const float sgn  = fmaf(s, 2.0f, -1.0f);   // +1/-1 exact
                    const float base = 1.0f - s;               //  0/+1 exact

                    // pg = (j - csf)*inv (clip inert: cd==0 on out-of-clip)
                    const float t0 = jf0 - csf, t1 = jf1 - csf, t2 = jf2 - csf;
                    const float pg0 = t0 * inv, pg1 = t1 * inv, pg2 = t2 * inv;

                    // mult = s ? pg : 1-pg, single-rounded fma (bit-equal)
                    const float m0 = fmaf(pg0, sgn, base);
                    const float m1 = fmaf(pg1, sgn, base);
                    const float m2 = fmaf(pg2, sgn, base);

                    // ---- STATE + OUTPUT products (HW-FTZ), ref scale ----
                    const float pr0 = cd0 * m0, pr1 = cd1 * m1, pr2 = cd2 * m2;
                    const float y0 = cd0 * pg0, y1 = cd1 * pg1, y2 = cd2 * pg2;

                    float p2, p1s;
                    row_total2((pr0 + pr1) + pr2, (y0 + y1) + y2, p2, p1s);

                    const float norm = fmaxf(p2, 1e-6f);   // clip(sum,1e-6,inf)
                    const float invn = __builtin_amdgcn_rcpf(norm);
                    cd0 = pr0 * invn; cd1 = pr1 * invn; cd2 = pr2 * invn;
                    csf += s;

                    // s1: ref p_z terms == norm terms exactly -> p2.
                    const float pz = (s != 0.0f) ? p2 : p1s;
                    mypz = (l16 == ii) ? pz : mypz;
                    nlast = p2;       // dead rows produce exactly 0
                }
                // p2==0 is absorbing per-row; all-zero ballot == total death.
                // Steps skipped after this produce pz=0 == prezeroed pzbuf.
                alive = __ballot(nlast != 0.0f) != 0ULL;
            }
        }
        pzbuf[(row * 16 + k) * 16 + l16] = mypz;   // off-chain stash
        return alive;
    };

    // ---- main loop: 2 k's per iteration, double-buffered loads ----
    float4 zpb0[4], ivb0[4], zpb1[4], ivb1[4];
#pragma unroll
    for (int c = 0; c < 4; ++c) {       // initial load: k=0 -> buf0
        zpb0[c] = *reinterpret_cast<const float4*>(presb + c * 4);
        ivb0[c] = *reinterpret_cast<const float4*>(&invt[c * 4]);
    }

#pragma unroll 1
    for (int kk = 0; kk < 8; ++kk) {
        const int k0 = 2 * kk, k1 = 2 * kk + 1;
        // prefetch k1 -> buf1 (first use ~16 steps away)
#pragma unroll
        for (int c = 0; c < 4; ++c) {
            zpb1[c] = *reinterpret_cast<const float4*>(presb + k1 * 16 + c * 4);
            ivb1[c] = *reinterpret_cast<const float4*>(&invt[k1 * 16 + c * 4]);
        }
        if (!do_k(k0, zpb0, ivb0)) break;

        // prefetch k0+2 -> buf0 (clamped; kk==7 load is unused, harmless)
        const int kn = (kk < 7) ? (k0 + 2) : 15;
#pragma unroll
        for (int c = 0; c < 4; ++c) {
            zpb0[c] = *reinterpret_cast<const float4*>(presb + kn * 16 + c * 4);
            ivb0[c] = *reinterpret_cast<const float4*>(&invt[kn * 16 + c * 4]);
        }
        if (!do_k(k1, zpb1, ivb1)) break;
    }

    // ---- KL epilogue: fast HW-log2 form ----
    // kl = ln2 * (prob*(Lp-Lz) + (1-prob)*(Lq-Lw)), L* = log2(x + 1e-9).
    // pz transported bit-exactly through LDS; unreached k's read exact +0
    // (Lw = log2(1+1e-9 -> 1.0f) = 0, matching ref's p_z=0 closed form).
    const float* probb = z_prob + (size_t)b * HW;
    float* outb = out + (size_t)b * HW;
#pragma unroll 4
    for (int k = 0; k < 16; ++k) {
        const float pz   = pzbuf[(row * 16 + k) * 16 + l16];
        const float prob = probb[k * 16 + l16];
        const float Lp = fast_log2(prob + 1e-9f);
        const float Lz = fast_log2(pz + 1e-9f);
        const float Lq = fast_log2((1.0f - prob) + 1e-9f);
        const float Lw = fast_log2((1.0f - pz) + 1e-9f);
        const float d1 = Lp - Lz;
        const float d2 = Lq - Lw;
        const float kl = 0.6931471805599453f * fmaf(prob, d1 - d2, d2);
        outb[k * 16 + l16] = kl;   // 64B per row, coalesced
    }
}

extern "C" void kernel_launch(void* const* d_in, const int* in_sizes, int n_in,
                              void* d_out, int out_size, void* d_ws, size_t ws_size,
                              hipStream_t stream) {
    const float* z_pres = (const float*)d_in[0];      // setup_inputs order
    const float* z_prob = (const float*)d_in[1];
    float* out = (float*)d_out;
    const int nbatch = in_sizes[0] / HW;              // 1024
    spair_count_kl<<<dim3(nbatch / 4), dim3(64), 0, stream>>>(z_pres, z_prob, out);
}